// Round 5
// baseline (20572.212 us; speedup 1.0000x reference)
//
#include <hip/hip_runtime.h>

// ---------------------------------------------------------------------------
// Persistent 2-layer GRU + output Linear for MI355X (gfx950).
// B=32, T=1024, I=128, H=512, O=128.  ALL I/O FP32 (reference dtypes).
// R5: 3-term bf16 split-precision (hi+lo) matmuls on the recurrent path to
// kill the 0.12 bf16 drift seen in R4. Rings store hi+lo bf16 planes; x is
// pre-split by a prepass kernel. Output Linear stays single-bf16 (terminal).
//
// 130 workgroups x 256 threads, all co-resident (1 WG/CU, LDS-bound):
//   WG   0..63  : layer-0, 8 h-cols each (24 gate rows + 8 pad, hi+lo in LDS)
//   WG  64..127 : layer-1, 8 h-cols each
//   WG 128..129 : output linear, 64 out-cols each (single bf16)
// Lockstep pipeline, one global flag-barrier per iteration (1026 iters).
// ---------------------------------------------------------------------------

typedef __attribute__((ext_vector_type(8))) short short8;
typedef __attribute__((ext_vector_type(4))) float floatx4;

#define MFMA_BF16(a, b, c) __builtin_amdgcn_mfma_f32_16x16x32_bf16(a, b, c, 0, 0, 0)

#define NWG 130
#define LDS_BYTES 156672  // 132096 weights (L1 hi+lo) + 24576 exchange
#define EX_REC 132096     // recurrent-WG exchange byte offset
#define EX_OUT 66560      // out-WG exchange byte offset (after 64x520x2B Wout)
#define HID_OFF 4194304   // fp32-elem offset of hidden outputs in d_out

// g_ws bytes: flags [0,1024) | y0 ring [1024, +131072) | y1 ring [+131072)
// ring: 2 slots x (hi plane 16384 + lo plane 16384) ushorts
__device__ __align__(16) unsigned g_ws[65792];
#define WS_WORDS 65792
__device__ __align__(16) unsigned short g_xhi[4194304];
__device__ __align__(16) unsigned short g_xlo[4194304];

static __device__ __forceinline__ float bf2f(unsigned short u) {
  unsigned v = ((unsigned)u) << 16;
  return __builtin_bit_cast(float, v);
}
static __device__ __forceinline__ unsigned short f2bf(float f) {
  unsigned u = __builtin_bit_cast(unsigned, f);
  u = (u + 0x7fffu + ((u >> 16) & 1u)) >> 16;  // RNE
  return (unsigned short)u;
}
static __device__ __forceinline__ float sigf(float x) {
  return 1.f / (1.f + __expf(-x));
}

extern "C" __global__ void gru_init() {
  int i = blockIdx.x * blockDim.x + threadIdx.x;
  if (i < WS_WORDS) g_ws[i] = 0u;
}

extern "C" __global__ void x_split(const float* __restrict__ x) {
  int i = blockIdx.x * 256 + threadIdx.x;
  if (i < 4194304) {
    float v = x[i];
    unsigned short h = f2bf(v);
    g_xhi[i] = h;
    g_xlo[i] = f2bf(v - bf2f(h));
  }
}

// ---- recurrent layer step: 8 h-cols, hi/lo split MFMA ----
template <int LAYER>
__device__ __forceinline__ void layer_step(
    int i, int tid, int q, int lm, int lq, int jb,
    const unsigned short* whi, const unsigned short* wlo, float* ex,
    unsigned short* y0ring, unsigned short* y1ring,
    float* __restrict__ dout,
    float bsr, float bsz, float bin, float bhn, float& hp) {
  constexpr int IHK = LAYER ? 512 : 128;
  constexpr int IHS = IHK / 32;        // ih k-steps
  constexpr int KSW = LAYER ? 8 : 5;   // k-steps per wave
  constexpr int WSTR = IHK + 512 + 8;  // LDS weight row stride (elems)

  const unsigned short* ih_base = nullptr;  // hi plane; lo at +16384
  const unsigned short* hh_base;
  if (LAYER == 0) {
    hh_base = y0ring + ((i + 1) & 1) * 32768;
  } else {
    ih_base = y0ring + ((i + 1) & 1) * 32768;
    hh_base = y1ring + (i & 1) * 32768;
  }

  const floatx4 z4 = {0.f, 0.f, 0.f, 0.f};
  floatx4 t0h[2] = {z4, z4}, t0l[2] = {z4, z4};        // tile0 (r,z rows)
  floatx4 tih_h[2] = {z4, z4}, tih_l[2] = {z4, z4};    // tile1 n, ih part
  floatx4 thh_h[2] = {z4, z4}, thh_l[2] = {z4, z4};    // tile1 n, hh part

#pragma unroll
  for (int s = 0; s < KSW; ++s) {
    int ks = q * KSW + s;
    int colk = ks * 32 + lq * 8;
    short8 ah[2], al[2];
    if (ks < IHS) {
      if (LAYER == 0) {  // pre-split x planes, layout (B,T,I)
        int p = i * 128 + colk;
        ah[0] = *(const short8*)(g_xhi + lm * 131072 + p);
        al[0] = *(const short8*)(g_xlo + lm * 131072 + p);
        ah[1] = *(const short8*)(g_xhi + (lm + 16) * 131072 + p);
        al[1] = *(const short8*)(g_xlo + (lm + 16) * 131072 + p);
      } else {
        const unsigned short* b = ih_base + lm * 512 + colk;
        ah[0] = *(const short8*)b;
        al[0] = *(const short8*)(b + 16384);
        b = ih_base + (lm + 16) * 512 + colk;
        ah[1] = *(const short8*)b;
        al[1] = *(const short8*)(b + 16384);
      }
    } else {
      int ck = colk - IHK;
      const unsigned short* b = hh_base + lm * 512 + ck;
      ah[0] = *(const short8*)b;
      al[0] = *(const short8*)(b + 16384);
      b = hh_base + (lm + 16) * 512 + ck;
      ah[1] = *(const short8*)b;
      al[1] = *(const short8*)(b + 16384);
    }
    short8 b0h = *(const short8*)(whi + lm * WSTR + colk);
    short8 b0l = *(const short8*)(wlo + lm * WSTR + colk);
    short8 b1h = *(const short8*)(whi + (16 + lm) * WSTR + colk);
    short8 b1l = *(const short8*)(wlo + (16 + lm) * WSTR + colk);
#pragma unroll
    for (int t = 0; t < 2; ++t) {
      t0h[t] = MFMA_BF16(ah[t], b0h, t0h[t]);
      t0l[t] = MFMA_BF16(ah[t], b0l, t0l[t]);
      t0l[t] = MFMA_BF16(al[t], b0h, t0l[t]);
      if (ks < IHS) {
        tih_h[t] = MFMA_BF16(ah[t], b1h, tih_h[t]);
        tih_l[t] = MFMA_BF16(ah[t], b1l, tih_l[t]);
        tih_l[t] = MFMA_BF16(al[t], b1h, tih_l[t]);
      } else {
        thh_h[t] = MFMA_BF16(ah[t], b1h, thh_h[t]);
        thh_l[t] = MFMA_BF16(ah[t], b1l, thh_l[t]);
        thh_l[t] = MFMA_BF16(al[t], b1h, thh_l[t]);
      }
    }
  }
  int lane = tid & 63;
#pragma unroll
  for (int t = 0; t < 2; ++t) {
    *(floatx4*)(ex + ((0 * 4 + q) * 2 + t) * 256 + lane * 4) = t0h[t] + t0l[t];
    *(floatx4*)(ex + ((1 * 4 + q) * 2 + t) * 256 + lane * 4) = tih_h[t] + tih_l[t];
    *(floatx4*)(ex + ((2 * 4 + q) * 2 + t) * 256 + lane * 4) = thh_h[t] + thh_l[t];
  }
  __syncthreads();

  // elementwise: thread owns (batch m = tid>>3, col j = tid&7)
  int m = tid >> 3, j = tid & 7;
  int quad = (m >> 2) & 3, reg = m & 3, mh = m >> 4;
  int offr = (quad * 16 + j) * 4 + reg;       // r rows 0..7 in tile0
  int offz = (quad * 16 + 8 + j) * 4 + reg;   // z rows 8..15 in tile0
  float sr = 0, sz = 0, sih = 0, shh = 0;
#pragma unroll
  for (int qq = 0; qq < 4; ++qq) {
    const float* s0 = ex + ((0 * 4 + qq) * 2 + mh) * 256;
    const float* s1 = ex + ((1 * 4 + qq) * 2 + mh) * 256;
    const float* s2 = ex + ((2 * 4 + qq) * 2 + mh) * 256;
    sr += s0[offr];
    sz += s0[offz];
    sih += s1[offr];
    shh += s2[offr];
  }
  float r = sigf(sr + bsr);
  float z = sigf(sz + bsz);
  float n = tanhf(sih + bin + r * (shh + bhn));
  float h = (1.f - z) * n + z * hp;
  hp = h;
  unsigned short hh16 = f2bf(h);
  unsigned short hl16 = f2bf(h - bf2f(hh16));
  unsigned short* dst =
      LAYER ? (y1ring + ((i + 1) & 1) * 32768) : (y0ring + (i & 1) * 32768);
  dst[m * 512 + jb + j] = hh16;
  dst[16384 + m * 512 + jb + j] = hl16;
  if (i == (LAYER ? 1024 : 1023))
    dout[HID_OFF + LAYER * 16384 + m * 512 + jb + j] = h;
}

__device__ __forceinline__ void out_step(
    int i, int tid, int lane, int q, int lm, int lq, int ob,
    const unsigned short* wl, float* ex,
    const unsigned short* y1ring,
    float* __restrict__ dout, const float* bo) {
  const unsigned short* A = y1ring + (i & 1) * 32768;  // y1[i-2] hi plane
  const floatx4 z4 = {0.f, 0.f, 0.f, 0.f};
  floatx4 acc[4][2];
#pragma unroll
  for (int nt = 0; nt < 4; ++nt) { acc[nt][0] = z4; acc[nt][1] = z4; }
#pragma unroll
  for (int s = 0; s < 4; ++s) {
    int ks = q * 4 + s;
    int colk = ks * 32 + lq * 8;
    short8 a0 = *(const short8*)(A + lm * 512 + colk);
    short8 a1 = *(const short8*)(A + (lm + 16) * 512 + colk);
#pragma unroll
    for (int nt = 0; nt < 4; ++nt) {
      short8 b = *(const short8*)(wl + (nt * 16 + lm) * 520 + colk);
      acc[nt][0] = MFMA_BF16(a0, b, acc[nt][0]);
      acc[nt][1] = MFMA_BF16(a1, b, acc[nt][1]);
    }
  }
#pragma unroll
  for (int nt = 0; nt < 4; ++nt) {
    *(floatx4*)(ex + ((q * 4 + nt) * 2 + 0) * 256 + lane * 4) = acc[nt][0];
    *(floatx4*)(ex + ((q * 4 + nt) * 2 + 1) * 256 + lane * 4) = acc[nt][1];
  }
  __syncthreads();
  int m = tid >> 3, oc = (tid & 7) * 8;
  int t_out = i - 2;
  float sv[8];
#pragma unroll
  for (int k = 0; k < 8; ++k) {
    int o = oc + k;
    int nt = o >> 4, jj = o & 15;
    int off = (((m >> 2) & 3) * 16 + jj) * 4 + (m & 3);
    int mh = m >> 4;
    float s = bo[k];
#pragma unroll
    for (int qq = 0; qq < 4; ++qq) s += ex[((qq * 4 + nt) * 2 + mh) * 256 + off];
    sv[k] = s;
  }
  float* dst = dout + m * 131072 + t_out * 128 + ob + oc;  // (B,T,O) fp32
  *(floatx4*)dst = floatx4{sv[0], sv[1], sv[2], sv[3]};
  *(floatx4*)(dst + 4) = floatx4{sv[4], sv[5], sv[6], sv[7]};
}

extern "C" __global__ void __launch_bounds__(256, 1) gru_main(
    const float* __restrict__ Wih0, const float* __restrict__ Whh0,
    const float* __restrict__ bih0, const float* __restrict__ bhh0,
    const float* __restrict__ Wih1, const float* __restrict__ Whh1,
    const float* __restrict__ bih1, const float* __restrict__ bhh1,
    const float* __restrict__ Wout, const float* __restrict__ boutp,
    float* __restrict__ dout) {
  extern __shared__ char smem[];
  __shared__ int sbail;

  int* flags = (int*)g_ws;
  unsigned short* y0ring = (unsigned short*)((char*)g_ws + 1024);
  unsigned short* y1ring = (unsigned short*)((char*)g_ws + 1024 + 131072);

  const int w = blockIdx.x;
  const int tid = threadIdx.x;
  const int lane = tid & 63;
  const int q = tid >> 6;
  const int lm = lane & 15;
  const int lq = lane >> 4;
  const int role = (w < 128) ? ((w < 64) ? 0 : 1) : 2;

  if (tid == 0) sbail = 0;

  unsigned short* whi = (unsigned short*)smem;
  float* ex = (float*)(smem + (role == 2 ? EX_OUT : EX_REC));
  // defensive: zero exchange region
  {
    int exn = (role == 2) ? 8192 : 6144;
    for (int idx = tid; idx < exn; idx += 256) ex[idx] = 0.f;
  }

  float bsr = 0, bsz = 0, bin = 0, bhn = 0;
  float bo[8] = {0, 0, 0, 0, 0, 0, 0, 0};
  int jb = 0, ob = 0;
  const unsigned short* wlo = nullptr;

  if (role < 2) {
    jb = (role == 0 ? w : w - 64) * 8;
    const int IHK = role ? 512 : 128;
    const int KTOT = IHK + 512;
    const int WSTR = KTOT + 8;
    unsigned short* wlo_w = whi + 32 * WSTR;
    wlo = wlo_w;
    const float* Wih = role ? Wih1 : Wih0;
    const float* Whh = role ? Whh1 : Whh0;
    const float* bih = role ? bih1 : bih0;
    const float* bhh = role ? bhh1 : bhh0;
    int cpr = KTOT / 8;
    for (int idx = tid; idx < 32 * cpr; idx += 256) {
      int r = idx / cpr, c = idx - r * cpr;
      int k0 = c * 8;
      short8 hi8 = {0, 0, 0, 0, 0, 0, 0, 0}, lo8 = {0, 0, 0, 0, 0, 0, 0, 0};
      if (r < 24) {  // rows 24..31 are zero pad
        int gate = r >> 3, jl = r & 7;
        int grow = gate * 512 + jb + jl;
        const float* src = (k0 < IHK) ? (Wih + grow * IHK + k0)
                                      : (Whh + grow * 512 + (k0 - IHK));
#pragma unroll
        for (int e = 0; e < 8; ++e) {
          float v = src[e];
          unsigned short h16 = f2bf(v);
          hi8[e] = (short)h16;
          lo8[e] = (short)f2bf(v - bf2f(h16));
        }
      }
      *(short8*)(whi + r * WSTR + k0) = hi8;
      *(short8*)(wlo_w + r * WSTR + k0) = lo8;
    }
    // zero the 8-elem row pads on both planes
    for (int idx = tid; idx < 32 * 8; idx += 256) {
      int r = idx >> 3, kk = KTOT + (idx & 7);
      whi[r * WSTR + kk] = 0;
      wlo_w[r * WSTR + kk] = 0;
    }
    int g0 = jb + (tid & 7);
    bsr = bih[g0] + bhh[g0];
    bsz = bih[512 + g0] + bhh[512 + g0];
    bin = bih[1024 + g0];
    bhn = bhh[1024 + g0];
  } else {
    ob = (w - 128) * 64;
    for (int idx = tid; idx < 64 * 64; idx += 256) {
      int r = idx >> 6, c = idx & 63;
      const float* src = Wout + (ob + r) * 512 + c * 8;
      short8 hi8;
#pragma unroll
      for (int e = 0; e < 8; ++e) hi8[e] = (short)f2bf(src[e]);
      *(short8*)(whi + r * 520 + c * 8) = hi8;
    }
    for (int idx = tid; idx < 64 * 8; idx += 256)
      whi[(idx >> 3) * 520 + 512 + (idx & 7)] = 0;
#pragma unroll
    for (int k = 0; k < 8; ++k) bo[k] = boutp[ob + (tid & 7) * 8 + k];
  }
  __syncthreads();

  float hp = 0.f;

  for (int i = 0; i < 1026; ++i) {
    bool active = (role == 0) ? (i < 1024)
                : (role == 1) ? (i >= 1 && i < 1025)
                              : (i >= 2);
    if (active) {
      if (role == 0) {
        layer_step<0>(i, tid, q, lm, lq, jb, whi, wlo, ex, y0ring, y1ring,
                      dout, bsr, bsz, bin, bhn, hp);
      } else if (role == 1) {
        layer_step<1>(i, tid, q, lm, lq, jb, whi, wlo, ex, y0ring, y1ring,
                      dout, bsr, bsz, bin, bhn, hp);
      } else {
        out_step(i, tid, lane, q, lm, lq, ob, whi, ex, y1ring, dout, bo);
      }
    }
    // ---- publish + global lockstep barrier (race-free per-thread poll) ----
    __builtin_amdgcn_fence(__ATOMIC_RELEASE, "agent");
    __syncthreads();
    if (tid == 0)
      __hip_atomic_store(&flags[w], i + 1, __ATOMIC_RELAXED, __HIP_MEMORY_SCOPE_AGENT);
    const int tgt = i + 1;
    if (tid < NWG) {
      int guard = 0;
      while (__hip_atomic_load(&flags[tid], __ATOMIC_RELAXED,
                               __HIP_MEMORY_SCOPE_AGENT) < tgt) {
        __builtin_amdgcn_s_sleep(1);
        if (++guard > (1 << 15)) { sbail = 1; break; }
      }
    }
    __syncthreads();
    __builtin_amdgcn_fence(__ATOMIC_ACQUIRE, "agent");
    if (sbail) break;
  }
}

extern "C" void kernel_launch(void* const* d_in, const int* in_sizes, int n_in,
                              void* d_out, int out_size, void* d_ws, size_t ws_size,
                              hipStream_t stream) {
  const float* x = (const float*)d_in[0];
  const float* Wih0 = (const float*)d_in[1];
  const float* Whh0 = (const float*)d_in[2];
  const float* bih0 = (const float*)d_in[3];
  const float* bhh0 = (const float*)d_in[4];
  const float* Wih1 = (const float*)d_in[5];
  const float* Whh1 = (const float*)d_in[6];
  const float* bih1 = (const float*)d_in[7];
  const float* bhh1 = (const float*)d_in[8];
  const float* Wout = (const float*)d_in[9];
  const float* bout = (const float*)d_in[10];

  hipLaunchKernelGGL(gru_init, dim3((WS_WORDS + 255) / 256), dim3(256), 0,
                     stream);
  hipLaunchKernelGGL(x_split, dim3(4194304 / 256), dim3(256), 0, stream, x);

  hipFuncSetAttribute((const void*)gru_main,
                      hipFuncAttributeMaxDynamicSharedMemorySize, LDS_BYTES);
  hipLaunchKernelGGL(gru_main, dim3(NWG), dim3(256), LDS_BYTES, stream,
                     Wih0, Whh0, bih0, bhh0, Wih1, Whh1, bih1, bhh1, Wout,
                     bout, (float*)d_out);
}

// Round 6
// 13525.432 us; speedup vs baseline: 1.5210x; 1.5210x over previous
//
#include <hip/hip_runtime.h>

// ---------------------------------------------------------------------------
// Persistent 2-layer GRU + output Linear for MI355X (gfx950).
// B=32, T=1024, I=128, H=512, O=128.  ALL I/O FP32 (reference dtypes).
// Split-precision (hi+lo bf16) matmuls on the recurrent path (R5, verified
// absmax 9.8e-4). R6: kill the 21 us/step sync cost:
//   - NO fences (no buffer_wbl2/buffer_inv per step). Cross-WG ring data
//     moves via agent-scope RELAXED ATOMIC loads/stores (sc0 sc1 -> MALL),
//     ordered by __syncthreads' vmcnt(0) drain before the flag store.
//   - Dataflow waits (deps >= i) instead of a global lockstep barrier.
//
// 130 workgroups x 256 threads, all co-resident (1 WG/CU, LDS-bound):
//   WG   0..63  : layer-0, 8 h-cols each (hi+lo weights in LDS)
//   WG  64..127 : layer-1, 8 h-cols each
//   WG 128..129 : output linear, 64 out-cols each (single bf16)
// Flag semantics: flags[w] = number of completed steps by WG w.
// Step-i waits (flag >= i == dep completed step i-1):
//   L0: needs L0 (y0[i-1] self-recurrence feed), L1 (frees y0 slot i&1)
//   L1: needs L0 (y0[i-1]), L1 (y1[i-1]), OUT (frees y1 slot (i+1)&1)
//   OUT: needs L1 (y1[i-2] in slot i&1)
// ---------------------------------------------------------------------------

typedef __attribute__((ext_vector_type(8))) short short8;
typedef __attribute__((ext_vector_type(4))) float floatx4;
typedef __attribute__((ext_vector_type(2))) unsigned long long ull2;

#define MFMA_BF16(a, b, c) __builtin_amdgcn_mfma_f32_16x16x32_bf16(a, b, c, 0, 0, 0)

#define NWG 130
#define LDS_BYTES 156672  // 132096 weights (L1 hi+lo) + 24576 exchange
#define EX_REC 132096     // recurrent-WG exchange byte offset
#define EX_OUT 66560      // out-WG exchange byte offset
#define HID_OFF 4194304   // fp32-elem offset of hidden outputs in d_out

// g_ws bytes: flags [0,1024) | y0 ring [1024, +131072) | y1 ring [+131072)
// ring: 2 slots x (hi plane 16384 + lo plane 16384) ushorts
__device__ __align__(16) unsigned g_ws[65792];
#define WS_WORDS 65792
__device__ __align__(16) unsigned short g_xhi[4194304];
__device__ __align__(16) unsigned short g_xlo[4194304];

static __device__ __forceinline__ float bf2f(unsigned short u) {
  unsigned v = ((unsigned)u) << 16;
  return __builtin_bit_cast(float, v);
}
static __device__ __forceinline__ unsigned short f2bf(float f) {
  unsigned u = __builtin_bit_cast(unsigned, f);
  u = (u + 0x7fffu + ((u >> 16) & 1u)) >> 16;  // RNE
  return (unsigned short)u;
}
static __device__ __forceinline__ float sigf(float x) {
  return 1.f / (1.f + __expf(-x));
}
// 16B coherent ring load: agent-scope relaxed atomics -> global_load sc0 sc1
// (bypasses the stale per-XCD L2, served from MALL). Compiler-tracked, so
// loads pipeline and vmcnt batches normally.
static __device__ __forceinline__ short8 ldring(const unsigned short* p) {
  ull2 t;
  t.x = __hip_atomic_load((const unsigned long long*)p, __ATOMIC_RELAXED,
                          __HIP_MEMORY_SCOPE_AGENT);
  t.y = __hip_atomic_load((const unsigned long long*)(p + 4), __ATOMIC_RELAXED,
                          __HIP_MEMORY_SCOPE_AGENT);
  return __builtin_bit_cast(short8, t);
}

extern "C" __global__ void gru_init() {
  int i = blockIdx.x * blockDim.x + threadIdx.x;
  if (i < WS_WORDS) g_ws[i] = 0u;
}

extern "C" __global__ void x_split(const float* __restrict__ x) {
  int i = blockIdx.x * 256 + threadIdx.x;
  if (i < 4194304) {
    float v = x[i];
    unsigned short h = f2bf(v);
    g_xhi[i] = h;
    g_xlo[i] = f2bf(v - bf2f(h));
  }
}

// ---- recurrent layer step: 8 h-cols, hi/lo split MFMA ----
template <int LAYER>
__device__ __forceinline__ void layer_step(
    int i, int tid, int q, int lm, int lq, int jb,
    const unsigned short* whi, const unsigned short* wlo, float* ex,
    unsigned short* y0ring, unsigned short* y1ring,
    float* __restrict__ dout,
    float bsr, float bsz, float bin, float bhn, float& hp) {
  constexpr int IHK = LAYER ? 512 : 128;
  constexpr int IHS = IHK / 32;        // ih k-steps
  constexpr int KSW = LAYER ? 8 : 5;   // k-steps per wave
  constexpr int WSTR = IHK + 512 + 8;  // LDS weight row stride (elems)

  const unsigned short* ih_base = nullptr;  // hi plane; lo at +16384
  const unsigned short* hh_base;
  if (LAYER == 0) {
    hh_base = y0ring + ((i + 1) & 1) * 32768;
  } else {
    ih_base = y0ring + ((i + 1) & 1) * 32768;
    hh_base = y1ring + (i & 1) * 32768;
  }

  const floatx4 z4 = {0.f, 0.f, 0.f, 0.f};
  floatx4 t0h[2] = {z4, z4}, t0l[2] = {z4, z4};      // tile0 (r,z rows)
  floatx4 tih_h[2] = {z4, z4}, tih_l[2] = {z4, z4};  // tile1 n, ih part
  floatx4 thh_h[2] = {z4, z4}, thh_l[2] = {z4, z4};  // tile1 n, hh part

#pragma unroll
  for (int s = 0; s < KSW; ++s) {
    int ks = q * KSW + s;
    int colk = ks * 32 + lq * 8;
    short8 ah[2], al[2];
    if (ks < IHS) {
      if (LAYER == 0) {  // pre-split x planes (read-only: plain loads ok)
        int p = i * 128 + colk;
        ah[0] = *(const short8*)(g_xhi + lm * 131072 + p);
        al[0] = *(const short8*)(g_xlo + lm * 131072 + p);
        ah[1] = *(const short8*)(g_xhi + (lm + 16) * 131072 + p);
        al[1] = *(const short8*)(g_xlo + (lm + 16) * 131072 + p);
      } else {
        const unsigned short* b = ih_base + lm * 512 + colk;
        ah[0] = ldring(b);
        al[0] = ldring(b + 16384);
        b = ih_base + (lm + 16) * 512 + colk;
        ah[1] = ldring(b);
        al[1] = ldring(b + 16384);
      }
    } else {
      int ck = colk - IHK;
      const unsigned short* b = hh_base + lm * 512 + ck;
      ah[0] = ldring(b);
      al[0] = ldring(b + 16384);
      b = hh_base + (lm + 16) * 512 + ck;
      ah[1] = ldring(b);
      al[1] = ldring(b + 16384);
    }
    short8 b0h = *(const short8*)(whi + lm * WSTR + colk);
    short8 b0l = *(const short8*)(wlo + lm * WSTR + colk);
    short8 b1h = *(const short8*)(whi + (16 + lm) * WSTR + colk);
    short8 b1l = *(const short8*)(wlo + (16 + lm) * WSTR + colk);
#pragma unroll
    for (int t = 0; t < 2; ++t) {
      t0h[t] = MFMA_BF16(ah[t], b0h, t0h[t]);
      t0l[t] = MFMA_BF16(ah[t], b0l, t0l[t]);
      t0l[t] = MFMA_BF16(al[t], b0h, t0l[t]);
      if (ks < IHS) {
        tih_h[t] = MFMA_BF16(ah[t], b1h, tih_h[t]);
        tih_l[t] = MFMA_BF16(ah[t], b1l, tih_l[t]);
        tih_l[t] = MFMA_BF16(al[t], b1h, tih_l[t]);
      } else {
        thh_h[t] = MFMA_BF16(ah[t], b1h, thh_h[t]);
        thh_l[t] = MFMA_BF16(ah[t], b1l, thh_l[t]);
        thh_l[t] = MFMA_BF16(al[t], b1h, thh_l[t]);
      }
    }
  }
  int lane = tid & 63;
#pragma unroll
  for (int t = 0; t < 2; ++t) {
    *(floatx4*)(ex + ((0 * 4 + q) * 2 + t) * 256 + lane * 4) = t0h[t] + t0l[t];
    *(floatx4*)(ex + ((1 * 4 + q) * 2 + t) * 256 + lane * 4) = tih_h[t] + tih_l[t];
    *(floatx4*)(ex + ((2 * 4 + q) * 2 + t) * 256 + lane * 4) = thh_h[t] + thh_l[t];
  }
  __syncthreads();

  // elementwise: thread owns (batch m = tid>>3, col j = tid&7)
  int m = tid >> 3, j = tid & 7;
  int quad = (m >> 2) & 3, reg = m & 3, mh = m >> 4;
  int offr = (quad * 16 + j) * 4 + reg;      // r rows 0..7 in tile0
  int offz = (quad * 16 + 8 + j) * 4 + reg;  // z rows 8..15 in tile0
  float sr = 0, sz = 0, sih = 0, shh = 0;
#pragma unroll
  for (int qq = 0; qq < 4; ++qq) {
    const float* s0 = ex + ((0 * 4 + qq) * 2 + mh) * 256;
    const float* s1 = ex + ((1 * 4 + qq) * 2 + mh) * 256;
    const float* s2 = ex + ((2 * 4 + qq) * 2 + mh) * 256;
    sr += s0[offr];
    sz += s0[offz];
    sih += s1[offr];
    shh += s2[offr];
  }
  float r = sigf(sr + bsr);
  float z = sigf(sz + bsz);
  float n = tanhf(sih + bin + r * (shh + bhn));
  float h = (1.f - z) * n + z * hp;
  hp = h;

  // pair-pack hi/lo bf16 words (atomics need >=32-bit) and store coherently
  unsigned short hh16 = f2bf(h);
  unsigned short hl16 = f2bf(h - bf2f(hh16));
  float hpart = __shfl_xor(h, 1);
  unsigned short ph16 = f2bf(hpart);
  unsigned short pl16 = f2bf(hpart - bf2f(ph16));
  unsigned short* dst =
      LAYER ? (y1ring + ((i + 1) & 1) * 32768) : (y0ring + (i & 1) * 32768);
  int colp = jb + (j & ~1);
  unsigned word;
  unsigned short* addr;
  if ((tid & 1) == 0) {  // hi-plane word: low=col j (self), high=col j+1
    word = ((unsigned)ph16 << 16) | (unsigned)hh16;
    addr = dst + m * 512 + colp;
  } else {               // lo-plane word: low=col j-1 (partner), high=self
    word = ((unsigned)hl16 << 16) | (unsigned)pl16;
    addr = dst + 16384 + m * 512 + colp;
  }
  __hip_atomic_store((unsigned*)addr, word, __ATOMIC_RELAXED,
                     __HIP_MEMORY_SCOPE_AGENT);

  if (i == (LAYER ? 1024 : 1023))  // final hidden state (fp32, plain store)
    dout[HID_OFF + LAYER * 16384 + m * 512 + jb + j] = h;
}

__device__ __forceinline__ void out_step(
    int i, int tid, int lane, int q, int lm, int lq, int ob,
    const unsigned short* wl, float* ex,
    const unsigned short* y1ring,
    float* __restrict__ dout, const float* bo) {
  const unsigned short* A = y1ring + (i & 1) * 32768;  // y1[i-2] hi plane
  const floatx4 z4 = {0.f, 0.f, 0.f, 0.f};
  floatx4 acc[4][2];
#pragma unroll
  for (int nt = 0; nt < 4; ++nt) { acc[nt][0] = z4; acc[nt][1] = z4; }
#pragma unroll
  for (int s = 0; s < 4; ++s) {
    int ks = q * 4 + s;
    int colk = ks * 32 + lq * 8;
    short8 a0 = ldring(A + lm * 512 + colk);
    short8 a1 = ldring(A + (lm + 16) * 512 + colk);
#pragma unroll
    for (int nt = 0; nt < 4; ++nt) {
      short8 b = *(const short8*)(wl + (nt * 16 + lm) * 520 + colk);
      acc[nt][0] = MFMA_BF16(a0, b, acc[nt][0]);
      acc[nt][1] = MFMA_BF16(a1, b, acc[nt][1]);
    }
  }
#pragma unroll
  for (int nt = 0; nt < 4; ++nt) {
    *(floatx4*)(ex + ((q * 4 + nt) * 2 + 0) * 256 + lane * 4) = acc[nt][0];
    *(floatx4*)(ex + ((q * 4 + nt) * 2 + 1) * 256 + lane * 4) = acc[nt][1];
  }
  __syncthreads();
  int m = tid >> 3, oc = (tid & 7) * 8;
  int t_out = i - 2;
  float sv[8];
#pragma unroll
  for (int k = 0; k < 8; ++k) {
    int o = oc + k;
    int nt = o >> 4, jj = o & 15;
    int off = (((m >> 2) & 3) * 16 + jj) * 4 + (m & 3);
    int mh = m >> 4;
    float s = bo[k];
#pragma unroll
    for (int qq = 0; qq < 4; ++qq) s += ex[((qq * 4 + nt) * 2 + mh) * 256 + off];
    sv[k] = s;
  }
  float* dst = dout + m * 131072 + t_out * 128 + ob + oc;  // (B,T,O) fp32
  *(floatx4*)dst = floatx4{sv[0], sv[1], sv[2], sv[3]};
  *(floatx4*)(dst + 4) = floatx4{sv[4], sv[5], sv[6], sv[7]};
}

extern "C" __global__ void __launch_bounds__(256, 1) gru_main(
    const float* __restrict__ Wih0, const float* __restrict__ Whh0,
    const float* __restrict__ bih0, const float* __restrict__ bhh0,
    const float* __restrict__ Wih1, const float* __restrict__ Whh1,
    const float* __restrict__ bih1, const float* __restrict__ bhh1,
    const float* __restrict__ Wout, const float* __restrict__ boutp,
    float* __restrict__ dout) {
  extern __shared__ char smem[];
  __shared__ int sbail;

  int* flags = (int*)g_ws;
  unsigned short* y0ring = (unsigned short*)((char*)g_ws + 1024);
  unsigned short* y1ring = (unsigned short*)((char*)g_ws + 1024 + 131072);

  const int w = blockIdx.x;
  const int tid = threadIdx.x;
  const int lane = tid & 63;
  const int q = tid >> 6;
  const int lm = lane & 15;
  const int lq = lane >> 4;
  const int role = (w < 128) ? ((w < 64) ? 0 : 1) : 2;

  if (tid == 0) sbail = 0;

  unsigned short* whi = (unsigned short*)smem;
  float* ex = (float*)(smem + (role == 2 ? EX_OUT : EX_REC));
  {
    int exn = (role == 2) ? 8192 : 6144;
    for (int idx = tid; idx < exn; idx += 256) ex[idx] = 0.f;
  }

  float bsr = 0, bsz = 0, bin = 0, bhn = 0;
  float bo[8] = {0, 0, 0, 0, 0, 0, 0, 0};
  int jb = 0, ob = 0;
  const unsigned short* wlo = nullptr;

  if (role < 2) {
    jb = (role == 0 ? w : w - 64) * 8;
    const int IHK = role ? 512 : 128;
    const int KTOT = IHK + 512;
    const int WSTR = KTOT + 8;
    unsigned short* wlo_w = whi + 32 * WSTR;
    wlo = wlo_w;
    const float* Wih = role ? Wih1 : Wih0;
    const float* Whh = role ? Whh1 : Whh0;
    const float* bih = role ? bih1 : bih0;
    const float* bhh = role ? bhh1 : bhh0;
    int cpr = KTOT / 8;
    for (int idx = tid; idx < 32 * cpr; idx += 256) {
      int r = idx / cpr, c = idx - r * cpr;
      int k0 = c * 8;
      short8 hi8 = {0, 0, 0, 0, 0, 0, 0, 0}, lo8 = {0, 0, 0, 0, 0, 0, 0, 0};
      if (r < 24) {  // rows 24..31 are zero pad
        int gate = r >> 3, jl = r & 7;
        int grow = gate * 512 + jb + jl;
        const float* src = (k0 < IHK) ? (Wih + grow * IHK + k0)
                                      : (Whh + grow * 512 + (k0 - IHK));
#pragma unroll
        for (int e = 0; e < 8; ++e) {
          float v = src[e];
          unsigned short h16 = f2bf(v);
          hi8[e] = (short)h16;
          lo8[e] = (short)f2bf(v - bf2f(h16));
        }
      }
      *(short8*)(whi + r * WSTR + k0) = hi8;
      *(short8*)(wlo_w + r * WSTR + k0) = lo8;
    }
    for (int idx = tid; idx < 32 * 8; idx += 256) {
      int r = idx >> 3, kk = KTOT + (idx & 7);
      whi[r * WSTR + kk] = 0;
      wlo_w[r * WSTR + kk] = 0;
    }
    int g0 = jb + (tid & 7);
    bsr = bih[g0] + bhh[g0];
    bsz = bih[512 + g0] + bhh[512 + g0];
    bin = bih[1024 + g0];
    bhn = bhh[1024 + g0];
  } else {
    ob = (w - 128) * 64;
    for (int idx = tid; idx < 64 * 64; idx += 256) {
      int r = idx >> 6, c = idx & 63;
      const float* src = Wout + (ob + r) * 512 + c * 8;
      short8 hi8;
#pragma unroll
      for (int e = 0; e < 8; ++e) hi8[e] = (short)f2bf(src[e]);
      *(short8*)(whi + r * 520 + c * 8) = hi8;
    }
    for (int idx = tid; idx < 64 * 8; idx += 256)
      whi[(idx >> 3) * 520 + 512 + (idx & 7)] = 0;
#pragma unroll
    for (int k = 0; k < 8; ++k) bo[k] = boutp[ob + (tid & 7) * 8 + k];
  }
  __syncthreads();

  float hp = 0.f;

  for (int i = 0; i < 1026; ++i) {
    // ---- dataflow wait: deps must have completed step i-1 (flag >= i) ----
    if (i > 0) {
      bool pollme = (role == 0) ? (tid < 128)
                  : (role == 1) ? (tid < 130)
                                : (tid < 64);
      if (pollme) {
        const int* fp = flags + ((role == 2) ? 64 + tid : tid);
        int guard = 0;
        while (__hip_atomic_load(fp, __ATOMIC_RELAXED,
                                 __HIP_MEMORY_SCOPE_AGENT) < i) {
          __builtin_amdgcn_s_sleep(1);
          if (++guard > (1 << 16)) { sbail = 1; break; }
        }
      }
    }
    __syncthreads();   // all deps observed by all threads
    if (sbail) break;

    bool active = (role == 0) ? (i < 1024)
                : (role == 1) ? (i >= 1 && i < 1025)
                              : (i >= 2);
    if (active) {
      if (role == 0) {
        layer_step<0>(i, tid, q, lm, lq, jb, whi, wlo, ex, y0ring, y1ring,
                      dout, bsr, bsz, bin, bhn, hp);
      } else if (role == 1) {
        layer_step<1>(i, tid, q, lm, lq, jb, whi, wlo, ex, y0ring, y1ring,
                      dout, bsr, bsz, bin, bhn, hp);
      } else {
        out_step(i, tid, lane, q, lm, lq, ob, whi, ex, y1ring, dout, bo);
      }
    }
    // ---- publish: drain this WG's stores (syncthreads waits vmcnt(0)),
    //      then one agent-scope flag store ----
    __syncthreads();
    if (tid == 0)
      __hip_atomic_store(&flags[w], i + 1, __ATOMIC_RELAXED,
                         __HIP_MEMORY_SCOPE_AGENT);
  }
}

extern "C" void kernel_launch(void* const* d_in, const int* in_sizes, int n_in,
                              void* d_out, int out_size, void* d_ws, size_t ws_size,
                              hipStream_t stream) {
  const float* x = (const float*)d_in[0];
  const float* Wih0 = (const float*)d_in[1];
  const float* Whh0 = (const float*)d_in[2];
  const float* bih0 = (const float*)d_in[3];
  const float* bhh0 = (const float*)d_in[4];
  const float* Wih1 = (const float*)d_in[5];
  const float* Whh1 = (const float*)d_in[6];
  const float* bih1 = (const float*)d_in[7];
  const float* bhh1 = (const float*)d_in[8];
  const float* Wout = (const float*)d_in[9];
  const float* bout = (const float*)d_in[10];

  hipLaunchKernelGGL(gru_init, dim3((WS_WORDS + 255) / 256), dim3(256), 0,
                     stream);
  hipLaunchKernelGGL(x_split, dim3(4194304 / 256), dim3(256), 0, stream, x);

  hipFuncSetAttribute((const void*)gru_main,
                      hipFuncAttributeMaxDynamicSharedMemorySize, LDS_BYTES);
  hipLaunchKernelGGL(gru_main, dim3(NWG), dim3(256), LDS_BYTES, stream,
                     Wih0, Whh0, bih0, bhh0, Wih1, Whh1, bih1, bhh1, Wout,
                     bout, (float*)d_out);
}

// Round 9
// 7517.913 us; speedup vs baseline: 2.7364x; 1.7991x over previous
//
#include <hip/hip_runtime.h>

// ---------------------------------------------------------------------------
// Persistent 2-layer GRU + output Linear for MI355X (gfx950).
// B=32, T=1024, I=128, H=512, O=128.  ALL I/O FP32 (reference dtypes).
// Split-precision (hi+lo bf16) matmuls on the recurrent path (verified
// absmax 9.8e-4 in R5/R6).
// R7 structure: fragment-layout rings (wave-contiguous 8B/lane sc-ops),
// x_arrange prepass, single-wave ballot polls, 4-deep rings.
// R9 fix: R7/R8 dropped PEER true dependencies. Each recurrent WG consumes
// the FULL h vector of its own layer (hh matmul) -> must wait for all 64
// peer WGs of the same layer, not just the other layer/out:
//   L0 step i: all L0 flags >= i (y0[t=i-1]), all L1 flags >= i-2 (slot free)
//   L1 step i: all L0 flags >= i (y0[t=i-1]), all L1 flags >= i (y1[t=i-2]),
//              OUT flags >= i-2 (slot free)
//   OUT step i: all L1 flags >= i (y1[t=i-2])
// (R6 passed because its poll was all-to-all; R7's "minimal" poll removed
// the peer deps -> 3-step race window on the 4-deep ring -> absmax ~3e-2.)
// Flag semantics: flags[w] = completed iterations. Writer step s -> slot s&3.
// ---------------------------------------------------------------------------

typedef __attribute__((ext_vector_type(8))) short short8;
typedef __attribute__((ext_vector_type(4))) float floatx4;
typedef __attribute__((ext_vector_type(2))) unsigned long long ull2;

#define MFMA_BF16(a, b, c) __builtin_amdgcn_mfma_f32_16x16x32_bf16(a, b, c, 0, 0, 0)

#define NWG 130
#define EX_REC 132096            // rec-WG exchange byte offset (after weights)
#define EX_OUT 66560             // out-WG exchange byte offset (after Wout)
#define HBUF_REC (EX_REC + 24576)
#define LDS_BYTES 157696         // weights 132096 + ex 24576 + hbuf 1024
#define HID_OFF 4194304          // fp32-elem offset of hidden outputs in d_out

// g_ws bytes: flags [0,1024) | y0 ring 4x64KB | y1 ring 4x64KB
__device__ __align__(16) unsigned g_ws[131328];
#define WS_WORDS 131328
// x in fragment layout: [t][kb(4)][tile(2)][hi 512 ushorts | lo 512]
__device__ __align__(16) unsigned short g_xf[8388608];

static __device__ __forceinline__ float bf2f(unsigned short u) {
  unsigned v = ((unsigned)u) << 16;
  return __builtin_bit_cast(float, v);
}
static __device__ __forceinline__ unsigned short f2bf(float f) {
  unsigned u = __builtin_bit_cast(unsigned, f);
  u = (u + 0x7fffu + ((u >> 16) & 1u)) >> 16;  // RNE
  return (unsigned short)u;
}
static __device__ __forceinline__ float sigf(float x) {
  return 1.f / (1.f + __expf(-x));
}
static __device__ __forceinline__ unsigned long long ld8(const unsigned short* p) {
  return __hip_atomic_load((const unsigned long long*)p, __ATOMIC_RELAXED,
                           __HIP_MEMORY_SCOPE_AGENT);
}
static __device__ __forceinline__ void st8(unsigned short* p, unsigned long long v) {
  __hip_atomic_store((unsigned long long*)p, v, __ATOMIC_RELAXED,
                     __HIP_MEMORY_SCOPE_AGENT);
}
// fragment block per (kb,tile): 1024 ushorts = [hiA|hiB|loA|loB][64 lanes][4us]
static __device__ __forceinline__ void ldfrag(const unsigned short* slot, int kb,
                                              int t, int lane, short8& hi,
                                              short8& lo) {
  const unsigned short* p = slot + (kb * 2 + t) * 1024 + lane * 4;
  ull2 h, l;
  h.x = ld8(p);
  h.y = ld8(p + 256);
  l.x = ld8(p + 512);
  l.y = ld8(p + 768);
  hi = __builtin_bit_cast(short8, h);
  lo = __builtin_bit_cast(short8, l);
}
static __device__ __forceinline__ unsigned long long pack4(const unsigned short* u) {
  return (unsigned long long)u[0] | ((unsigned long long)u[1] << 16) |
         ((unsigned long long)u[2] << 32) | ((unsigned long long)u[3] << 48);
}

extern "C" __global__ void gru_init() {
  int i = blockIdx.x * blockDim.x + threadIdx.x;
  if (i < WS_WORDS) g_ws[i] = 0u;
}

extern "C" __global__ void x_arrange(const float* __restrict__ x) {
  int gid = blockIdx.x * 256 + threadIdx.x;  // 524288 total
  int t = gid >> 9;
  int rem = gid & 511;
  int kb = rem >> 7;
  int tile = (rem >> 6) & 1;
  int lane = rem & 63;
  int b = tile * 16 + (lane & 15);
  int k = kb * 32 + (lane >> 4) * 8;
  const float* src = x + b * 131072 + t * 128 + k;  // x is (B,T,I)
  short8 hi, lo;
#pragma unroll
  for (int e = 0; e < 8; ++e) {
    float v = src[e];
    unsigned short h = f2bf(v);
    hi[e] = (short)h;
    lo[e] = (short)f2bf(v - bf2f(h));
  }
  unsigned short* dst = g_xf + ((t * 4 + kb) * 2 + tile) * 1024;
  *(short8*)(dst + lane * 8) = hi;
  *(short8*)(dst + 512 + lane * 8) = lo;
}

// ---- recurrent layer step: 8 h-cols, hi/lo split MFMA ----
template <int LAYER>
__device__ __forceinline__ void layer_step(
    int i, int tid, int q, int lane, int jb,
    const unsigned short* whi, const unsigned short* wlo, float* ex, float* hbuf,
    unsigned short* y0ring, unsigned short* y1ring,
    float* __restrict__ dout,
    float bsr, float bsz, float bin, float bhn, float& hp) {
  constexpr int IHK = LAYER ? 512 : 128;
  constexpr int IHS = IHK / 32;        // ih k-blocks
  constexpr int KSW = LAYER ? 8 : 5;   // k-steps per wave
  constexpr int WSTR = IHK + 512 + 8;  // LDS weight row stride (elems)
  const int lm = lane & 15, lq = lane >> 4;

  const unsigned short* ihs =
      LAYER ? (y0ring + ((i - 1) & 3) * 32768) : (const unsigned short*)nullptr;
  const unsigned short* hhs =
      (LAYER ? y1ring : y0ring) + ((i - 1) & 3) * 32768;

  const floatx4 z4 = {0.f, 0.f, 0.f, 0.f};
  floatx4 t0h[2] = {z4, z4}, t0l[2] = {z4, z4};      // tile0 (r,z rows)
  floatx4 tih_h[2] = {z4, z4}, tih_l[2] = {z4, z4};  // tile1 n, ih part
  floatx4 thh_h[2] = {z4, z4}, thh_l[2] = {z4, z4};  // tile1 n, hh part

#pragma unroll
  for (int s = 0; s < KSW; ++s) {
    int ks = q * KSW + s;
    int colk = ks * 32 + lq * 8;
    short8 ah[2], al[2];
    if (ks < IHS) {
      if (LAYER == 0) {  // fragment-layout x, normal cached loads
        const unsigned short* xb = g_xf + (i * 4 + ks) * 2048;
        ah[0] = *(const short8*)(xb + lane * 8);
        al[0] = *(const short8*)(xb + 512 + lane * 8);
        ah[1] = *(const short8*)(xb + 1024 + lane * 8);
        al[1] = *(const short8*)(xb + 1536 + lane * 8);
      } else {
        ldfrag(ihs, ks, 0, lane, ah[0], al[0]);
        ldfrag(ihs, ks, 1, lane, ah[1], al[1]);
      }
    } else {
      ldfrag(hhs, ks - IHS, 0, lane, ah[0], al[0]);
      ldfrag(hhs, ks - IHS, 1, lane, ah[1], al[1]);
    }
    short8 b0h = *(const short8*)(whi + lm * WSTR + colk);
    short8 b0l = *(const short8*)(wlo + lm * WSTR + colk);
    short8 b1h = *(const short8*)(whi + (16 + lm) * WSTR + colk);
    short8 b1l = *(const short8*)(wlo + (16 + lm) * WSTR + colk);
#pragma unroll
    for (int t = 0; t < 2; ++t) {
      t0h[t] = MFMA_BF16(ah[t], b0h, t0h[t]);
      t0l[t] = MFMA_BF16(ah[t], b0l, t0l[t]);
      t0l[t] = MFMA_BF16(al[t], b0h, t0l[t]);
      if (ks < IHS) {
        tih_h[t] = MFMA_BF16(ah[t], b1h, tih_h[t]);
        tih_l[t] = MFMA_BF16(ah[t], b1l, tih_l[t]);
        tih_l[t] = MFMA_BF16(al[t], b1h, tih_l[t]);
      } else {
        thh_h[t] = MFMA_BF16(ah[t], b1h, thh_h[t]);
        thh_l[t] = MFMA_BF16(ah[t], b1l, thh_l[t]);
        thh_l[t] = MFMA_BF16(al[t], b1h, thh_l[t]);
      }
    }
  }
#pragma unroll
  for (int t = 0; t < 2; ++t) {
    *(floatx4*)(ex + ((0 * 4 + q) * 2 + t) * 256 + lane * 4) = t0h[t] + t0l[t];
    *(floatx4*)(ex + ((1 * 4 + q) * 2 + t) * 256 + lane * 4) = tih_h[t] + tih_l[t];
    *(floatx4*)(ex + ((2 * 4 + q) * 2 + t) * 256 + lane * 4) = thh_h[t] + thh_l[t];
  }
  __syncthreads();

  // elementwise: thread owns (batch m = tid>>3, col j = tid&7)
  int m = tid >> 3, j = tid & 7;
  int quad = (m >> 2) & 3, reg = m & 3, mh = m >> 4;
  int offr = (quad * 16 + j) * 4 + reg;      // r rows 0..7 in tile0
  int offz = (quad * 16 + 8 + j) * 4 + reg;  // z rows 8..15 in tile0
  float sr = 0, sz = 0, sih = 0, shh = 0;
#pragma unroll
  for (int qq = 0; qq < 4; ++qq) {
    const float* s0 = ex + ((0 * 4 + qq) * 2 + mh) * 256;
    const float* s1 = ex + ((1 * 4 + qq) * 2 + mh) * 256;
    const float* s2 = ex + ((2 * 4 + qq) * 2 + mh) * 256;
    sr += s0[offr];
    sz += s0[offz];
    sih += s1[offr];
    shh += s2[offr];
  }
  float r = sigf(sr + bsr);
  float z = sigf(sz + bsz);
  float n = tanhf(sih + bin + r * (shh + bhn));
  float h = (1.f - z) * n + z * hp;
  hp = h;
  hbuf[m * 8 + j] = h;
  if (i == (LAYER ? 1024 : 1023))  // final hidden state (fp32)
    dout[HID_OFF + LAYER * 16384 + m * 512 + jb + j] = h;
  __syncthreads();

  // 32 threads write this WG's 8 columns into the fragment-layout ring slot
  if (tid < 32) {
    int mm = tid;
    int t = mm >> 4;
    int lanep = (mm & 15) + 16 * ((jb >> 3) & 3);
    int kb = jb >> 5;
    unsigned short h4[8], l4[8];
#pragma unroll
    for (int e = 0; e < 8; ++e) {
      float v = hbuf[mm * 8 + e];
      unsigned short hh = f2bf(v);
      h4[e] = hh;
      l4[e] = f2bf(v - bf2f(hh));
    }
    unsigned short* slot = (LAYER ? y1ring : y0ring) + (i & 3) * 32768;
    unsigned short* p = slot + (kb * 2 + t) * 1024 + lanep * 4;
    st8(p, pack4(h4));
    st8(p + 256, pack4(h4 + 4));
    st8(p + 512, pack4(l4));
    st8(p + 768, pack4(l4 + 4));
  }
}

__device__ __forceinline__ void out_step(
    int i, int tid, int lane, int q, int ob,
    const unsigned short* wl, float* ex,
    unsigned short* y1ring, float* __restrict__ dout, const float* bo) {
  const int lm = lane & 15, lq = lane >> 4;
  const unsigned short* slot = y1ring + ((i - 1) & 3) * 32768;  // y1[t=i-2]
  const floatx4 z4 = {0.f, 0.f, 0.f, 0.f};
  floatx4 acc[4][2];
#pragma unroll
  for (int nt = 0; nt < 4; ++nt) { acc[nt][0] = z4; acc[nt][1] = z4; }
#pragma unroll
  for (int s = 0; s < 4; ++s) {
    int ks = q * 4 + s;
    int colk = ks * 32 + lq * 8;
    short8 a0, a1;
    {
      const unsigned short* p = slot + (ks * 2 + 0) * 1024 + lane * 4;
      ull2 hv;
      hv.x = ld8(p);
      hv.y = ld8(p + 256);
      a0 = __builtin_bit_cast(short8, hv);
      p = slot + (ks * 2 + 1) * 1024 + lane * 4;
      hv.x = ld8(p);
      hv.y = ld8(p + 256);
      a1 = __builtin_bit_cast(short8, hv);
    }
#pragma unroll
    for (int nt = 0; nt < 4; ++nt) {
      short8 b = *(const short8*)(wl + (nt * 16 + lm) * 520 + colk);
      acc[nt][0] = MFMA_BF16(a0, b, acc[nt][0]);
      acc[nt][1] = MFMA_BF16(a1, b, acc[nt][1]);
    }
  }
#pragma unroll
  for (int nt = 0; nt < 4; ++nt) {
    *(floatx4*)(ex + ((q * 4 + nt) * 2 + 0) * 256 + lane * 4) = acc[nt][0];
    *(floatx4*)(ex + ((q * 4 + nt) * 2 + 1) * 256 + lane * 4) = acc[nt][1];
  }
  __syncthreads();
  int m = tid >> 3, oc = (tid & 7) * 8;
  int t_out = i - 2;
  float sv[8];
#pragma unroll
  for (int k = 0; k < 8; ++k) {
    int o = oc + k;
    int nt = o >> 4, jj = o & 15;
    int off = (((m >> 2) & 3) * 16 + jj) * 4 + (m & 3);
    int mh = m >> 4;
    float s = bo[k];
#pragma unroll
    for (int qq = 0; qq < 4; ++qq) s += ex[((qq * 4 + nt) * 2 + mh) * 256 + off];
    sv[k] = s;
  }
  float* dst = dout + m * 131072 + t_out * 128 + ob + oc;  // (B,T,O) fp32
  *(floatx4*)dst = floatx4{sv[0], sv[1], sv[2], sv[3]};
  *(floatx4*)(dst + 4) = floatx4{sv[4], sv[5], sv[6], sv[7]};
}

extern "C" __global__ void __launch_bounds__(256, 1) gru_main(
    const float* __restrict__ Wih0, const float* __restrict__ Whh0,
    const float* __restrict__ bih0, const float* __restrict__ bhh0,
    const float* __restrict__ Wih1, const float* __restrict__ Whh1,
    const float* __restrict__ bih1, const float* __restrict__ bhh1,
    const float* __restrict__ Wout, const float* __restrict__ boutp,
    float* __restrict__ dout) {
  extern __shared__ char smem[];
  __shared__ int sbail;

  int* flags = (int*)g_ws;
  unsigned short* y0ring = (unsigned short*)((char*)g_ws + 1024);
  unsigned short* y1ring = (unsigned short*)((char*)g_ws + 1024 + 262144);

  const int w = blockIdx.x;
  const int tid = threadIdx.x;
  const int lane = tid & 63;
  const int q = tid >> 6;
  const int role = (w < 128) ? ((w < 64) ? 0 : 1) : 2;

  if (tid == 0) sbail = 0;

  unsigned short* whi = (unsigned short*)smem;
  float* ex = (float*)(smem + (role == 2 ? EX_OUT : EX_REC));
  float* hbuf = (float*)(smem + HBUF_REC);
  {
    int exn = (role == 2) ? 8192 : 6144;
    for (int idx = tid; idx < exn; idx += 256) ex[idx] = 0.f;
  }

  float bsr = 0, bsz = 0, bin = 0, bhn = 0;
  float bo[8] = {0, 0, 0, 0, 0, 0, 0, 0};
  int jb = 0, ob = 0;
  const unsigned short* wlo = nullptr;

  if (role < 2) {
    jb = (role == 0 ? w : w - 64) * 8;
    const int IHK = role ? 512 : 128;
    const int KTOT = IHK + 512;
    const int WSTR = KTOT + 8;
    unsigned short* wlo_w = whi + 32 * WSTR;
    wlo = wlo_w;
    const float* Wih = role ? Wih1 : Wih0;
    const float* Whh = role ? Whh1 : Whh0;
    const float* bih = role ? bih1 : bih0;
    const float* bhh = role ? bhh1 : bhh0;
    int cpr = KTOT / 8;
    for (int idx = tid; idx < 32 * cpr; idx += 256) {
      int r = idx / cpr, c = idx - r * cpr;
      int k0 = c * 8;
      short8 hi8 = {0, 0, 0, 0, 0, 0, 0, 0}, lo8 = {0, 0, 0, 0, 0, 0, 0, 0};
      if (r < 24) {  // rows 24..31 zero pad
        int gate = r >> 3, jl = r & 7;
        int grow = gate * 512 + jb + jl;
        const float* src = (k0 < IHK) ? (Wih + grow * IHK + k0)
                                      : (Whh + grow * 512 + (k0 - IHK));
#pragma unroll
        for (int e = 0; e < 8; ++e) {
          float v = src[e];
          unsigned short h16 = f2bf(v);
          hi8[e] = (short)h16;
          lo8[e] = (short)f2bf(v - bf2f(h16));
        }
      }
      *(short8*)(whi + r * WSTR + k0) = hi8;
      *(short8*)(wlo_w + r * WSTR + k0) = lo8;
    }
    for (int idx = tid; idx < 32 * 8; idx += 256) {
      int r = idx >> 3, kk = KTOT + (idx & 7);
      whi[r * WSTR + kk] = 0;
      wlo_w[r * WSTR + kk] = 0;
    }
    int g0 = jb + (tid & 7);
    bsr = bih[g0] + bhh[g0];
    bsz = bih[512 + g0] + bhh[512 + g0];
    bin = bih[1024 + g0];
    bhn = bhh[1024 + g0];
  } else {
    ob = (w - 128) * 64;
    for (int idx = tid; idx < 64 * 64; idx += 256) {
      int r = idx >> 6, c = idx & 63;
      const float* src = Wout + (ob + r) * 512 + c * 8;
      short8 hi8;
#pragma unroll
      for (int e = 0; e < 8; ++e) hi8[e] = (short)f2bf(src[e]);
      *(short8*)(whi + r * 520 + c * 8) = hi8;
    }
    for (int idx = tid; idx < 64 * 8; idx += 256)
      whi[(idx >> 3) * 520 + 512 + (idx & 7)] = 0;
#pragma unroll
    for (int k = 0; k < 8; ++k) bo[k] = boutp[ob + (tid & 7) * 8 + k];
  }
  __syncthreads();

  float hp = 0.f;

  for (int i = 0; i < 1026; ++i) {
    // ---- single-wave ballot poll (peer deps INCLUDED — see header) ----
    if (i > 0 && tid < 64) {
      int guard = 0;
      for (;;) {
        bool ok;
        if (role == 0) {
          // true dep: all L0 peers finished i-1 (y0[t=i-1] complete);
          // anti-dep: all L1 finished i-3 (y0 slot i&3 free)
          ok = (__hip_atomic_load(flags + tid, __ATOMIC_RELAXED,
                                  __HIP_MEMORY_SCOPE_AGENT) >= i) &&
               (__hip_atomic_load(flags + 64 + tid, __ATOMIC_RELAXED,
                                  __HIP_MEMORY_SCOPE_AGENT) >= i - 2);
        } else if (role == 1) {
          // true deps: all L0 >= i (y0[t=i-1]); all L1 peers >= i (y1[t=i-2]);
          // anti-dep: OUT finished i-3 (y1 slot i&3 free)
          ok = (__hip_atomic_load(flags + tid, __ATOMIC_RELAXED,
                                  __HIP_MEMORY_SCOPE_AGENT) >= i) &&
               (__hip_atomic_load(flags + 64 + tid, __ATOMIC_RELAXED,
                                  __HIP_MEMORY_SCOPE_AGENT) >= i);
          if (tid < 2)
            ok = ok && (__hip_atomic_load(flags + 128 + tid, __ATOMIC_RELAXED,
                                          __HIP_MEMORY_SCOPE_AGENT) >= i - 2);
        } else {
          // OUT: true dep all L1 >= i (y1[t=i-2] complete)
          ok = __hip_atomic_load(flags + 64 + tid, __ATOMIC_RELAXED,
                                 __HIP_MEMORY_SCOPE_AGENT) >= i;
        }
        if (__ballot(ok) == ~0ull) break;
        __builtin_amdgcn_s_sleep(1);
        if (++guard > (1 << 17)) { sbail = 1; break; }
      }
    }
    __syncthreads();
    if (sbail) break;

    bool active = (role == 0) ? (i < 1024)
                : (role == 1) ? (i >= 1 && i < 1025)
                              : (i >= 2);
    if (active) {
      if (role == 0) {
        layer_step<0>(i, tid, q, lane, jb, whi, wlo, ex, hbuf, y0ring, y1ring,
                      dout, bsr, bsz, bin, bhn, hp);
      } else if (role == 1) {
        layer_step<1>(i, tid, q, lane, jb, whi, wlo, ex, hbuf, y0ring, y1ring,
                      dout, bsr, bsz, bin, bhn, hp);
      } else {
        out_step(i, tid, lane, q, ob, whi, ex, y1ring, dout, bo);
      }
    }
    // ---- publish: barrier drains vmcnt (ring stores at MALL), then flag ----
    __syncthreads();
    if (tid == 0)
      __hip_atomic_store(&flags[w], i + 1, __ATOMIC_RELAXED,
                         __HIP_MEMORY_SCOPE_AGENT);
  }
}

extern "C" void kernel_launch(void* const* d_in, const int* in_sizes, int n_in,
                              void* d_out, int out_size, void* d_ws, size_t ws_size,
                              hipStream_t stream) {
  const float* x = (const float*)d_in[0];
  const float* Wih0 = (const float*)d_in[1];
  const float* Whh0 = (const float*)d_in[2];
  const float* bih0 = (const float*)d_in[3];
  const float* bhh0 = (const float*)d_in[4];
  const float* Wih1 = (const float*)d_in[5];
  const float* Whh1 = (const float*)d_in[6];
  const float* bih1 = (const float*)d_in[7];
  const float* bhh1 = (const float*)d_in[8];
  const float* Wout = (const float*)d_in[9];
  const float* bout = (const float*)d_in[10];

  hipLaunchKernelGGL(gru_init, dim3((WS_WORDS + 255) / 256), dim3(256), 0,
                     stream);
  hipLaunchKernelGGL(x_arrange, dim3(524288 / 256), dim3(256), 0, stream, x);

  hipFuncSetAttribute((const void*)gru_main,
                      hipFuncAttributeMaxDynamicSharedMemorySize, LDS_BYTES);
  hipLaunchKernelGGL(gru_main, dim3(NWG), dim3(256), LDS_BYTES, stream,
                     Wih0, Whh0, bih0, bhh0, Wih1, Whh1, bih1, bhh1, Wout,
                     bout, (float*)d_out);
}